// Round 8
// baseline (5690.487 us; speedup 1.0000x reference)
//
#include <hip/hip_runtime.h>

#define V_N 20000
#define E_N 100000
#define NODE_IN_F 128
#define EDGE_IN_F 128
#define H 64
#define EDGE_HID 128
#define OUT_F 64
#define STEPS 9

typedef __attribute__((ext_vector_type(8))) short bf16x8;
typedef __attribute__((ext_vector_type(4))) float f32x4;

__device__ __forceinline__ unsigned short f2bf(float f) {
    union { float f; unsigned int u; } v; v.f = f;
    unsigned int u = v.u;
    unsigned int r = (u + 0x7fffu + ((u >> 16) & 1u)) >> 16;  // RNE
    return (unsigned short)r;
}
__device__ __forceinline__ float bfbits(unsigned int u16) {
    union { unsigned int u; float f; } v; v.u = u16 << 16; return v.f;
}
// dot of 2 packed bf16 pairs
__device__ __forceinline__ float dot2bf(unsigned int a, unsigned int b) {
    union { unsigned int u; float f; } alo, ahi, blo, bhi;
    alo.u = a << 16; ahi.u = a & 0xffff0000u;
    blo.u = b << 16; bhi.u = b & 0xffff0000u;
    return alo.f * blo.f + ahi.f * bhi.f;
}
__device__ __forceinline__ float dot4(float4 w, float4 x) {
    return w.x * x.x + w.y * x.y + w.z * x.z + w.w * x.w;
}

// h0 = relu(nf@w1.T+b1)@w2.T+b2; zero agg & deg; hb = h0 @ b_e2; hb16/hb16lo = split(h0)
// 4 nodes / 256-thread block (wave per node) -> 4x weight-read reuse vs 64-thr blocks.
__global__ __launch_bounds__(256) void k_project(
    const float* __restrict__ nf,
    const float* __restrict__ w1, const float* __restrict__ b1,
    const float* __restrict__ w2, const float* __restrict__ b2,
    const float* __restrict__ b2e,
    float* __restrict__ h, float* __restrict__ agg, float* __restrict__ hb,
    unsigned short* __restrict__ hb16, unsigned short* __restrict__ hb16lo,
    int* __restrict__ deg)
{
    int wv = threadIdx.x >> 6, t = threadIdx.x & 63;
    int v = blockIdx.x * 4 + wv;
    __shared__ float x[4][132], tm[4][68];
    const float* row = nf + (size_t)v * NODE_IN_F;
    x[wv][t] = row[t];
    x[wv][t + 64] = row[t + 64];
    agg[(size_t)v * H + t] = 0.f;
    if (t == 0) deg[v] = 0;
    __syncthreads();
    float acc = b1[t];
    const float4* wr = (const float4*)(w1 + (size_t)t * NODE_IN_F);
    #pragma unroll
    for (int q = 0; q < NODE_IN_F / 4; ++q) acc += dot4(wr[q], *(const float4*)&x[wv][q * 4]);
    tm[wv][t] = fmaxf(acc, 0.f);
    __syncthreads();
    float acc2 = b2[t];
    const float4* wr2 = (const float4*)(w2 + (size_t)t * H);
    #pragma unroll
    for (int q = 0; q < H / 4; ++q) acc2 += dot4(wr2[q], *(const float4*)&tm[wv][q * 4]);
    size_t p = (size_t)v * H + t;
    h[p] = acc2;
    unsigned short hi = f2bf(acc2);
    hb16[p] = hi;
    hb16lo[p] = f2bf(acc2 - bfbits(hi));
    __syncthreads();
    x[wv][t] = acc2;
    __syncthreads();
    float acc3 = 0.f;
    for (int i = 0; i < H; ++i) acc3 += x[wv][i] * b2e[i * 64 + t];
    hb[p] = acc3;
}

// g = relu(ef @ w_e1.T + b_e1) -> (E,128) bf16
__global__ __launch_bounds__(256) void k_edge_g(
    const float* __restrict__ ef,
    const float* __restrict__ w1, const float* __restrict__ b1,
    unsigned short* __restrict__ g)
{
    int tid = threadIdx.x;
    int e0 = blockIdx.x * 32;
    int c = tid & 127, eg = tid >> 7;
    __shared__ float xe[32][132];
    for (int idx = tid; idx < 1024; idx += 256) {
        int e = idx >> 5, kq = idx & 31;
        float4 v = *(const float4*)(ef + (size_t)(e0 + e) * EDGE_IN_F + kq * 4);
        *(float4*)&xe[e][kq * 4] = v;
    }
    __syncthreads();
    float acc[16];
    #pragma unroll
    for (int j = 0; j < 16; ++j) acc[j] = b1[c];
    const float4* wr = (const float4*)(w1 + (size_t)c * EDGE_IN_F);
    for (int kb = 0; kb < EDGE_IN_F / 4; ++kb) {
        float4 w = wr[kb];
        #pragma unroll
        for (int j = 0; j < 16; ++j) {
            float4 x = *(const float4*)&xe[eg * 16 + j][kb * 4];
            acc[j] += dot4(w, x);
        }
    }
    #pragma unroll
    for (int j = 0; j < 16; ++j)
        g[(size_t)(e0 + eg * 16 + j) * EDGE_HID + c] = f2bf(fmaxf(acc[j], 0.f));
}

// w2rr[c][i] = bf16(w_e2[(i*64+o)*128 + k]), c = o*128+k. (8192 x 64 bf16, 1 MB)
__global__ __launch_bounds__(256) void k_w2rr(
    const float* __restrict__ w2, unsigned short* __restrict__ w2rr)
{
    int f = blockIdx.x * 256 + threadIdx.x;   // 0..524287
    int i = f & 63;
    int c = f >> 6;
    int o = c >> 7;
    int k = c & 127;
    w2rr[f] = f2bf(w2[(size_t)(i * 64 + o) * 128 + k]);
}

// CSR build (src static; rebuilt identically every call)
__global__ __launch_bounds__(256) void k_hist(const int* __restrict__ src, int* __restrict__ deg) {
    int e = blockIdx.x * 256 + threadIdx.x;
    if (e < E_N) atomicAdd(&deg[src[e]], 1);
}

__global__ __launch_bounds__(256) void k_scan(
    const int* __restrict__ deg, int* __restrict__ rowptr, int* __restrict__ cursor)
{
    const int CH = 79;   // 256*79 >= V_N
    int t = threadIdx.x;
    __shared__ int part[256];
    int base = t * CH, s = 0;
    for (int j = 0; j < CH; ++j) { int v = base + j; if (v < V_N) s += deg[v]; }
    part[t] = s;
    __syncthreads();
    if (t == 0) { int run = 0; for (int i = 0; i < 256; ++i) { int x = part[i]; part[i] = run; run += x; } }
    __syncthreads();
    int run = part[t];
    for (int j = 0; j < CH; ++j) {
        int v = base + j;
        if (v < V_N) { rowptr[v] = run; cursor[v] = run; run += deg[v]; }
    }
    if (t == 255) rowptr[V_N] = E_N;
}

__global__ __launch_bounds__(256) void k_scatter(
    const int* __restrict__ src, int* __restrict__ cursor, int* __restrict__ esort)
{
    int e = blockIdx.x * 256 + threadIdx.x;
    if (e < E_N) {
        int p = atomicAdd(&cursor[src[e]], 1);
        esort[p] = e;
    }
}

// Fused NNConv step: block = 16 nodes (nb..nb+16) + their out-edges (CSR).
// 8 c-chunks of 1024 (o-range 8 each):
//  Phase A (MFMA, layouts verified by r7 k_nmat pass): N[n, c] = sum_i h[n,i]*w2rr[c,i]
//    into LDS tile [n][o_loc][k] (o-stride 136, n-stride 1096 elems -> <=2-way banks).
//  Phase B: wave per edge; lane = og*8+kg (8 o x 8 k-groups of 16);
//    partial = dot(g[e,kslice], N_lds[nloc,o,kslice]); butterfly over kg;
//    8-lane coalesced atomicAdd into agg[dst] (+hb for this o-range).
__global__ __launch_bounds__(256) void k_fused(
    const unsigned short* __restrict__ hb16, const unsigned short* __restrict__ hb16lo,
    const unsigned short* __restrict__ w2rr, const unsigned short* __restrict__ g,
    const float* __restrict__ hb, const int* __restrict__ rowptr,
    const int* __restrict__ esort, const int* __restrict__ src,
    const int* __restrict__ dst, float* __restrict__ agg)
{
    int tid = threadIdx.x;
    int wv = tid >> 6, lane = tid & 63;
    int m = lane & 15, q = lane >> 4;
    int nb = blockIdx.x * 16;
    __shared__ unsigned short n_lds[16 * 1096];   // 35072 B
    int r0 = rowptr[nb], r1 = rowptr[nb + 16];
    // A fragments: 16 node rows (lane m = node nb+m), hi/lo split, K=64 over i
    const unsigned short* pa = hb16 + (size_t)(nb + m) * 64 + q * 8;
    const unsigned short* pl = hb16lo + (size_t)(nb + m) * 64 + q * 8;
    bf16x8 ah0 = *(const bf16x8*)(pa);
    bf16x8 ah1 = *(const bf16x8*)(pa + 32);
    bf16x8 al0 = *(const bf16x8*)(pl);
    bf16x8 al1 = *(const bf16x8*)(pl + 32);
    int og = lane >> 3, kg = lane & 7;

    for (int cc = 0; cc < 8; ++cc) {
        __syncthreads();   // previous chunk's phase-B reads complete
        // ---- Phase A ----
        #pragma unroll 2
        for (int t = 0; t < 16; ++t) {
            int tile = wv * 16 + t;               // 0..63
            int c0 = cc * 1024 + tile * 16;
            const unsigned short* pb = w2rr + (size_t)(c0 + m) * 64 + q * 8;
            bf16x8 b0 = *(const bf16x8*)(pb);
            bf16x8 b1 = *(const bf16x8*)(pb + 32);
            f32x4 d = {0.f, 0.f, 0.f, 0.f};
            d = __builtin_amdgcn_mfma_f32_16x16x32_bf16(al0, b0, d, 0, 0, 0);
            d = __builtin_amdgcn_mfma_f32_16x16x32_bf16(al1, b1, d, 0, 0, 0);
            d = __builtin_amdgcn_mfma_f32_16x16x32_bf16(ah0, b0, d, 0, 0, 0);
            d = __builtin_amdgcn_mfma_f32_16x16x32_bf16(ah1, b1, d, 0, 0, 0);
            int cl = tile * 16 + m;               // 0..1023 (same o for all 16 m)
            int ol = cl >> 7, k = cl & 127;
            #pragma unroll
            for (int r = 0; r < 4; ++r) {
                int n = q * 4 + r;
                n_lds[n * 1096 + ol * 136 + k] = f2bf(d[r]);
            }
        }
        __syncthreads();
        // ---- Phase B ----
        for (int j = r0 + wv; j < r1; j += 4) {
            int e = esort[j];
            int v = src[e];                       // in [nb, nb+16)
            int nloc = v - nb;
            const uint4* gp = (const uint4*)(g + (size_t)e * EDGE_HID + kg * 16);
            uint4 g0 = gp[0], g1 = gp[1];
            const uint4* np = (const uint4*)&n_lds[nloc * 1096 + og * 136 + kg * 16];
            uint4 n0 = np[0], n1 = np[1];
            float s = dot2bf(g0.x, n0.x) + dot2bf(g0.y, n0.y)
                    + dot2bf(g0.z, n0.z) + dot2bf(g0.w, n0.w)
                    + dot2bf(g1.x, n1.x) + dot2bf(g1.y, n1.y)
                    + dot2bf(g1.z, n1.z) + dot2bf(g1.w, n1.w);
            s += __shfl_xor(s, 1);
            s += __shfl_xor(s, 2);
            s += __shfl_xor(s, 4);
            if (kg == 0) {
                int o = cc * 8 + og;
                float val = s + hb[(size_t)v * 64 + o];
                atomicAdd(&agg[(size_t)dst[e] * 64 + o], val);
            }
        }
    }
}

// GRU; epilogue: hb = newh @ b_e2, hb16/hb16lo = split(newh); agg re-zeroed
__global__ __launch_bounds__(256) void k_gru(
    float* __restrict__ agg, const float* __restrict__ b_conv,
    const float* __restrict__ w_ih, const float* __restrict__ w_hh,
    const float* __restrict__ b_ih, const float* __restrict__ b_hh,
    const float* __restrict__ b2e,
    float* __restrict__ h, float* __restrict__ hb,
    unsigned short* __restrict__ hb16, unsigned short* __restrict__ hb16lo)
{
    int tid = threadIdx.x;
    int o = tid & 63, grp = tid >> 6;
    int vbase = blockIdx.x * 16;
    __shared__ float xl[16][68], hl[16][68];
    for (int idx = tid; idx < 16 * 64; idx += 256) {
        int n = idx >> 6, i = idx & 63;
        size_t p = (size_t)(vbase + n) * H + i;
        float a = agg[p];
        agg[p] = 0.f;
        xl[n][i] = fmaxf(a + b_conv[i], 0.f);
        hl[n][i] = h[p];
    }
    __syncthreads();
    float gir[4], giz[4], gin[4], ghr[4], ghz[4], ghn[4];
    #pragma unroll
    for (int n = 0; n < 4; ++n) {
        gir[n] = b_ih[o];       ghr[n] = b_hh[o];
        giz[n] = b_ih[64 + o];  ghz[n] = b_hh[64 + o];
        gin[n] = b_ih[128 + o]; ghn[n] = b_hh[128 + o];
    }
    const float4* wir = (const float4*)(w_ih + (size_t)o * H);
    const float4* wiz = (const float4*)(w_ih + (size_t)(64 + o) * H);
    const float4* win = (const float4*)(w_ih + (size_t)(128 + o) * H);
    const float4* whr = (const float4*)(w_hh + (size_t)o * H);
    const float4* whz = (const float4*)(w_hh + (size_t)(64 + o) * H);
    const float4* whn = (const float4*)(w_hh + (size_t)(128 + o) * H);
    #pragma unroll 4
    for (int qq = 0; qq < H / 4; ++qq) {
        float4 a1 = wir[qq], a2 = wiz[qq], a3 = win[qq];
        float4 c1 = whr[qq], c2 = whz[qq], c3 = whn[qq];
        #pragma unroll
        for (int n = 0; n < 4; ++n) {
            float4 xv = *(const float4*)&xl[grp * 4 + n][qq * 4];
            float4 hv = *(const float4*)&hl[grp * 4 + n][qq * 4];
            gir[n] += dot4(a1, xv); giz[n] += dot4(a2, xv); gin[n] += dot4(a3, xv);
            ghr[n] += dot4(c1, hv); ghz[n] += dot4(c2, hv); ghn[n] += dot4(c3, hv);
        }
    }
    float newh[4];
    #pragma unroll
    for (int n = 0; n < 4; ++n) {
        float hv = hl[grp * 4 + n][o];
        float r = 1.f / (1.f + __expf(-(gir[n] + ghr[n])));
        float z = 1.f / (1.f + __expf(-(giz[n] + ghz[n])));
        float na = gin[n] + r * ghn[n];
        float tn = 1.f - 2.f / (__expf(2.f * na) + 1.f);   // tanh
        newh[n] = (1.f - z) * tn + z * hv;
        size_t p = (size_t)(vbase + grp * 4 + n) * H + o;
        h[p] = newh[n];
        unsigned short hi = f2bf(newh[n]);
        hb16[p] = hi;
        hb16lo[p] = f2bf(newh[n] - bfbits(hi));
    }
    __syncthreads();
    #pragma unroll
    for (int n = 0; n < 4; ++n) xl[grp * 4 + n][o] = newh[n];
    __syncthreads();
    float hbacc[4] = {0.f, 0.f, 0.f, 0.f};
    for (int i = 0; i < H; ++i) {
        float w = b2e[i * 64 + o];
        #pragma unroll
        for (int n = 0; n < 4; ++n) hbacc[n] += xl[grp * 4 + n][i] * w;
    }
    #pragma unroll
    for (int n = 0; n < 4; ++n)
        hb[(size_t)(vbase + grp * 4 + n) * H + o] = hbacc[n];
}

// out = relu(h @ w_d1.T + b_d1) @ w_d2.T + b_d2  -> fp32
__global__ __launch_bounds__(64) void k_decoder(
    const float* __restrict__ h,
    const float* __restrict__ w1, const float* __restrict__ b1,
    const float* __restrict__ w2, const float* __restrict__ b2,
    float* __restrict__ out)
{
    int v = blockIdx.x, t = threadIdx.x;
    __shared__ float hl[H], tl[H];
    hl[t] = h[(size_t)v * H + t];
    __syncthreads();
    float acc = b1[t];
    const float4* wr = (const float4*)(w1 + (size_t)t * H);
    #pragma unroll
    for (int q = 0; q < H / 4; ++q) acc += dot4(wr[q], *(const float4*)&hl[q * 4]);
    tl[t] = fmaxf(acc, 0.f);
    __syncthreads();
    float acc2 = b2[t];
    const float4* wr2 = (const float4*)(w2 + (size_t)t * H);
    #pragma unroll
    for (int q = 0; q < H / 4; ++q) acc2 += dot4(wr2[q], *(const float4*)&tl[q * 4]);
    out[(size_t)v * OUT_F + t] = acc2;
}

extern "C" void kernel_launch(void* const* d_in, const int* in_sizes, int n_in,
                              void* d_out, int out_size, void* d_ws, size_t ws_size,
                              hipStream_t stream) {
    const float* nf     = (const float*)d_in[0];
    const float* ef     = (const float*)d_in[1];
    const int* src      = (const int*)d_in[2];
    const int* dst      = (const int*)d_in[3];
    const float* w_p1   = (const float*)d_in[4];
    const float* b_p1   = (const float*)d_in[5];
    const float* w_p2   = (const float*)d_in[6];
    const float* b_p2   = (const float*)d_in[7];
    const float* w_e1   = (const float*)d_in[8];
    const float* b_e1   = (const float*)d_in[9];
    const float* w_e2   = (const float*)d_in[10];
    const float* b_e2   = (const float*)d_in[11];
    const float* b_conv = (const float*)d_in[12];
    const float* w_ih   = (const float*)d_in[13];
    const float* w_hh   = (const float*)d_in[14];
    const float* b_ih   = (const float*)d_in[15];
    const float* b_hh   = (const float*)d_in[16];
    const float* w_d1   = (const float*)d_in[17];
    const float* b_d1   = (const float*)d_in[18];
    const float* w_d2   = (const float*)d_in[19];
    const float* b_d2   = (const float*)d_in[20];

    // workspace layout (~47.8 MB, offsets 1024-aligned)
    char* ws = (char*)d_ws;
    size_t off = 0;
    unsigned short* g      = (unsigned short*)(ws + off); off += 25600000;   // E*128 bf16
    unsigned short* w2rr   = (unsigned short*)(ws + off); off += 1048576;    // 8192*64 bf16
    float* h               = (float*)(ws + off);          off += 5120000;    // V*64 f32
    float* agg             = (float*)(ws + off);          off += 5120000;
    float* hb              = (float*)(ws + off);          off += 5120000;
    unsigned short* hb16   = (unsigned short*)(ws + off); off += 2560000;    // V*64 bf16
    unsigned short* hb16lo = (unsigned short*)(ws + off); off += 2560000;
    int* deg               = (int*)(ws + off);            off += 80896;
    int* cursor            = (int*)(ws + off);            off += 80896;
    int* rowptr            = (int*)(ws + off);            off += 80896;      // V+1 ints
    int* esort             = (int*)(ws + off);            off += 400384;     // E ints

    k_project<<<V_N / 4, 256, 0, stream>>>(nf, w_p1, b_p1, w_p2, b_p2, b_e2,
                                           h, agg, hb, hb16, hb16lo, deg);
    k_edge_g<<<E_N / 32, 256, 0, stream>>>(ef, w_e1, b_e1, g);
    k_w2rr<<<2048, 256, 0, stream>>>(w_e2, w2rr);
    k_hist<<<(E_N + 255) / 256, 256, 0, stream>>>(src, deg);
    k_scan<<<1, 256, 0, stream>>>(deg, rowptr, cursor);
    k_scatter<<<(E_N + 255) / 256, 256, 0, stream>>>(src, cursor, esort);

    for (int s = 0; s < STEPS; ++s) {
        k_fused<<<V_N / 16, 256, 0, stream>>>(hb16, hb16lo, w2rr, g, hb,
                                              rowptr, esort, src, dst, agg);
        k_gru<<<V_N / 16, 256, 0, stream>>>(agg, b_conv, w_ih, w_hh, b_ih, b_hh,
                                            b_e2, h, hb, hb16, hb16lo);
    }
    k_decoder<<<V_N, 64, 0, stream>>>(h, w_d1, b_d1, w_d2, b_d2, (float*)d_out);
}

// Round 9
// 4340.634 us; speedup vs baseline: 1.3110x; 1.3110x over previous
//
#include <hip/hip_runtime.h>

#define V_N 20000
#define E_N 100000
#define NODE_IN_F 128
#define EDGE_IN_F 128
#define H 64
#define EDGE_HID 128
#define OUT_F 64
#define STEPS 9
#define OS 136                 // o-stride (elements) in n_lds: 272B, 16B-aligned
#define NS (8 * OS)            // node stride: 1088 elements
#define NED_CAP 256            // staged-edge cap per block (avg 80, P(>256)~0)

typedef __attribute__((ext_vector_type(8))) short bf16x8;
typedef __attribute__((ext_vector_type(4))) float f32x4;

__device__ __forceinline__ unsigned short f2bf(float f) {
    union { float f; unsigned int u; } v; v.f = f;
    unsigned int u = v.u;
    unsigned int r = (u + 0x7fffu + ((u >> 16) & 1u)) >> 16;  // RNE
    return (unsigned short)r;
}
__device__ __forceinline__ float bfbits(unsigned int u16) {
    union { unsigned int u; float f; } v; v.u = u16 << 16; return v.f;
}
// dot of 2 packed bf16 pairs
__device__ __forceinline__ float dot2bf(unsigned int a, unsigned int b) {
    union { unsigned int u; float f; } alo, ahi, blo, bhi;
    alo.u = a << 16; ahi.u = a & 0xffff0000u;
    blo.u = b << 16; bhi.u = b & 0xffff0000u;
    return alo.f * blo.f + ahi.f * bhi.f;
}
__device__ __forceinline__ float dot4(float4 w, float4 x) {
    return w.x * x.x + w.y * x.y + w.z * x.z + w.w * x.w;
}

// h0 = relu(nf@w1.T+b1)@w2.T+b2; zero agg & deg; hb = h0 @ b_e2; hb16/hb16lo = split(h0)
__global__ __launch_bounds__(256) void k_project(
    const float* __restrict__ nf,
    const float* __restrict__ w1, const float* __restrict__ b1,
    const float* __restrict__ w2, const float* __restrict__ b2,
    const float* __restrict__ b2e,
    float* __restrict__ h, float* __restrict__ agg, float* __restrict__ hb,
    unsigned short* __restrict__ hb16, unsigned short* __restrict__ hb16lo,
    int* __restrict__ deg)
{
    int wv = threadIdx.x >> 6, t = threadIdx.x & 63;
    int v = blockIdx.x * 4 + wv;
    __shared__ float x[4][132], tm[4][68];
    const float* row = nf + (size_t)v * NODE_IN_F;
    x[wv][t] = row[t];
    x[wv][t + 64] = row[t + 64];
    agg[(size_t)v * H + t] = 0.f;
    if (t == 0) deg[v] = 0;
    __syncthreads();
    float acc = b1[t];
    const float4* wr = (const float4*)(w1 + (size_t)t * NODE_IN_F);
    #pragma unroll
    for (int q = 0; q < NODE_IN_F / 4; ++q) acc += dot4(wr[q], *(const float4*)&x[wv][q * 4]);
    tm[wv][t] = fmaxf(acc, 0.f);
    __syncthreads();
    float acc2 = b2[t];
    const float4* wr2 = (const float4*)(w2 + (size_t)t * H);
    #pragma unroll
    for (int q = 0; q < H / 4; ++q) acc2 += dot4(wr2[q], *(const float4*)&tm[wv][q * 4]);
    size_t p = (size_t)v * H + t;
    h[p] = acc2;
    unsigned short hi = f2bf(acc2);
    hb16[p] = hi;
    hb16lo[p] = f2bf(acc2 - bfbits(hi));
    __syncthreads();
    x[wv][t] = acc2;
    __syncthreads();
    float acc3 = 0.f;
    for (int i = 0; i < H; ++i) acc3 += x[wv][i] * b2e[i * 64 + t];
    hb[p] = acc3;
}

// g = relu(ef @ w_e1.T + b_e1) -> (E,128) bf16
__global__ __launch_bounds__(256) void k_edge_g(
    const float* __restrict__ ef,
    const float* __restrict__ w1, const float* __restrict__ b1,
    unsigned short* __restrict__ g)
{
    int tid = threadIdx.x;
    int e0 = blockIdx.x * 32;
    int c = tid & 127, eg = tid >> 7;
    __shared__ float xe[32][132];
    for (int idx = tid; idx < 1024; idx += 256) {
        int e = idx >> 5, kq = idx & 31;
        float4 v = *(const float4*)(ef + (size_t)(e0 + e) * EDGE_IN_F + kq * 4);
        *(float4*)&xe[e][kq * 4] = v;
    }
    __syncthreads();
    float acc[16];
    #pragma unroll
    for (int j = 0; j < 16; ++j) acc[j] = b1[c];
    const float4* wr = (const float4*)(w1 + (size_t)c * EDGE_IN_F);
    for (int kb = 0; kb < EDGE_IN_F / 4; ++kb) {
        float4 w = wr[kb];
        #pragma unroll
        for (int j = 0; j < 16; ++j) {
            float4 x = *(const float4*)&xe[eg * 16 + j][kb * 4];
            acc[j] += dot4(w, x);
        }
    }
    #pragma unroll
    for (int j = 0; j < 16; ++j)
        g[(size_t)(e0 + eg * 16 + j) * EDGE_HID + c] = f2bf(fmaxf(acc[j], 0.f));
}

// w2rr[c][i] = bf16(w_e2[(i*64+o)*128 + k]), c = o*128+k. (8192 x 64 bf16, 1 MB)
__global__ __launch_bounds__(256) void k_w2rr(
    const float* __restrict__ w2, unsigned short* __restrict__ w2rr)
{
    int f = blockIdx.x * 256 + threadIdx.x;   // 0..524287
    int i = f & 63;
    int c = f >> 6;
    int o = c >> 7;
    int k = c & 127;
    w2rr[f] = f2bf(w2[(size_t)(i * 64 + o) * 128 + k]);
}

// CSR build (src static; rebuilt identically every call)
__global__ __launch_bounds__(256) void k_hist(const int* __restrict__ src, int* __restrict__ deg) {
    int e = blockIdx.x * 256 + threadIdx.x;
    if (e < E_N) atomicAdd(&deg[src[e]], 1);
}

__global__ __launch_bounds__(256) void k_scan(
    const int* __restrict__ deg, int* __restrict__ rowptr, int* __restrict__ cursor)
{
    const int CH = 79;   // 256*79 >= V_N
    int t = threadIdx.x;
    __shared__ int part[256];
    int base = t * CH, s = 0;
    for (int j = 0; j < CH; ++j) { int v = base + j; if (v < V_N) s += deg[v]; }
    part[t] = s;
    __syncthreads();
    if (t == 0) { int run = 0; for (int i = 0; i < 256; ++i) { int x = part[i]; part[i] = run; run += x; } }
    __syncthreads();
    int run = part[t];
    for (int j = 0; j < CH; ++j) {
        int v = base + j;
        if (v < V_N) { rowptr[v] = run; cursor[v] = run; run += deg[v]; }
    }
    if (t == 255) rowptr[V_N] = E_N;
}

__global__ __launch_bounds__(256) void k_scatter(
    const int* __restrict__ src, int* __restrict__ cursor, int* __restrict__ esort)
{
    int e = blockIdx.x * 256 + threadIdx.x;
    if (e < E_N) {
        int p = atomicAdd(&cursor[src[e]], 1);
        esort[p] = e;
    }
}

// Fused NNConv step: block = 16 nodes + their out-edges (CSR), 8 c-chunks of 1024.
// Phase A (MFMA, verified layouts): N[n][o][k] tile into LDS (o-stride 136).
// Phase B: wave per edge; lane=(og,kg); metadata PRE-STAGED in LDS (no pointer
// chase), g row software-pipelined 1 iter ahead; butterfly over kg; 8-lane
// coalesced atomicAdd.
__global__ __launch_bounds__(256) void k_fused(
    const unsigned short* __restrict__ hb16, const unsigned short* __restrict__ hb16lo,
    const unsigned short* __restrict__ w2rr, const unsigned short* __restrict__ g,
    const float* __restrict__ hb, const int* __restrict__ rowptr,
    const int* __restrict__ esort, const int* __restrict__ src,
    const int* __restrict__ dst, float* __restrict__ agg)
{
    int tid = threadIdx.x;
    int wv = tid >> 6, lane = tid & 63;
    int m = lane & 15, q = lane >> 4;
    int nb = blockIdx.x * 16;
    __shared__ unsigned short n_lds[16 * NS];   // 34816 B
    __shared__ int ed_e[NED_CAP], ed_d[NED_CAP];
    __shared__ float hb_s[16][68];
    int r0 = rowptr[nb], r1 = rowptr[nb + 16];
    int ntot = r1 - r0;
    int ned = ntot < NED_CAP ? ntot : NED_CAP;
    // ---- one-time staging: edge metadata + hb ----
    for (int idx = tid; idx < ned; idx += 256) {
        int e = esort[r0 + idx];
        ed_e[idx] = e | ((src[e] - nb) << 20);
        ed_d[idx] = dst[e];
    }
    for (int idx = tid; idx < 1024; idx += 256) {
        int n = idx >> 6, i = idx & 63;
        hb_s[n][i] = hb[(size_t)(nb + n) * 64 + i];
    }
    // A fragments: 16 node rows (lane m = node nb+m), hi/lo split, K=64 over i
    const unsigned short* pa = hb16 + (size_t)(nb + m) * 64 + q * 8;
    const unsigned short* pl = hb16lo + (size_t)(nb + m) * 64 + q * 8;
    bf16x8 ah0 = *(const bf16x8*)(pa);
    bf16x8 ah1 = *(const bf16x8*)(pa + 32);
    bf16x8 al0 = *(const bf16x8*)(pl);
    bf16x8 al1 = *(const bf16x8*)(pl + 32);
    int og = lane >> 3, kg = lane & 7;
    __syncthreads();

    for (int cc = 0; cc < 8; ++cc) {
        if (cc) __syncthreads();   // previous chunk's phase-B reads complete
        // ---- Phase A ----
        #pragma unroll 2
        for (int t = 0; t < 16; ++t) {
            int tile = wv * 16 + t;               // 0..63
            int c0 = cc * 1024 + tile * 16;
            const unsigned short* pb = w2rr + (size_t)(c0 + m) * 64 + q * 8;
            bf16x8 b0 = *(const bf16x8*)(pb);
            bf16x8 b1 = *(const bf16x8*)(pb + 32);
            f32x4 d = {0.f, 0.f, 0.f, 0.f};
            d = __builtin_amdgcn_mfma_f32_16x16x32_bf16(al0, b0, d, 0, 0, 0);
            d = __builtin_amdgcn_mfma_f32_16x16x32_bf16(al1, b1, d, 0, 0, 0);
            d = __builtin_amdgcn_mfma_f32_16x16x32_bf16(ah0, b0, d, 0, 0, 0);
            d = __builtin_amdgcn_mfma_f32_16x16x32_bf16(ah1, b1, d, 0, 0, 0);
            int cl = tile * 16 + m;               // 0..1023
            int ol = cl >> 7, k = cl & 127;
            #pragma unroll
            for (int r = 0; r < 4; ++r) {
                int n = q * 4 + r;
                n_lds[n * NS + ol * OS + k] = f2bf(d[r]);
            }
        }
        __syncthreads();
        // ---- Phase B (staged metadata, pipelined g) ----
        int o = cc * 8 + og;
        int j = wv;
        int pk = 0, dd = 0;
        uint4 gc0 = {0,0,0,0}, gc1 = {0,0,0,0};
        if (j < ned) {
            pk = ed_e[j]; dd = ed_d[j];
            const uint4* gp = (const uint4*)(g + (size_t)(pk & 0xfffff) * EDGE_HID + kg * 16);
            gc0 = gp[0]; gc1 = gp[1];
        }
        while (j < ned) {
            int jn = j + 4;
            int pk_n = 0, dd_n = 0;
            uint4 gn0 = {0,0,0,0}, gn1 = {0,0,0,0};
            if (jn < ned) {
                pk_n = ed_e[jn]; dd_n = ed_d[jn];
                const uint4* gp = (const uint4*)(g + (size_t)(pk_n & 0xfffff) * EDGE_HID + kg * 16);
                gn0 = gp[0]; gn1 = gp[1];
            }
            int nloc = pk >> 20;
            const uint4* np = (const uint4*)&n_lds[nloc * NS + og * OS + kg * 16];
            uint4 n0 = np[0], n1 = np[1];
            float s = dot2bf(gc0.x, n0.x) + dot2bf(gc0.y, n0.y)
                    + dot2bf(gc0.z, n0.z) + dot2bf(gc0.w, n0.w)
                    + dot2bf(gc1.x, n1.x) + dot2bf(gc1.y, n1.y)
                    + dot2bf(gc1.z, n1.z) + dot2bf(gc1.w, n1.w);
            s += __shfl_xor(s, 1);
            s += __shfl_xor(s, 2);
            s += __shfl_xor(s, 4);
            if (kg == 0)
                atomicAdd(&agg[(size_t)dd * 64 + o], s + hb_s[nloc][o]);
            pk = pk_n; dd = dd_n; gc0 = gn0; gc1 = gn1;
            j = jn;
        }
        // overflow path (ntot > NED_CAP): statistically never, correctness only
        for (int jj = NED_CAP + wv; jj < ntot; jj += 4) {
            int e = esort[r0 + jj];
            int nloc = src[e] - nb;
            int dd2 = dst[e];
            const uint4* gp = (const uint4*)(g + (size_t)e * EDGE_HID + kg * 16);
            uint4 g0 = gp[0], g1 = gp[1];
            const uint4* np = (const uint4*)&n_lds[nloc * NS + og * OS + kg * 16];
            uint4 n0 = np[0], n1 = np[1];
            float s = dot2bf(g0.x, n0.x) + dot2bf(g0.y, n0.y)
                    + dot2bf(g0.z, n0.z) + dot2bf(g0.w, n0.w)
                    + dot2bf(g1.x, n1.x) + dot2bf(g1.y, n1.y)
                    + dot2bf(g1.z, n1.z) + dot2bf(g1.w, n1.w);
            s += __shfl_xor(s, 1);
            s += __shfl_xor(s, 2);
            s += __shfl_xor(s, 4);
            if (kg == 0)
                atomicAdd(&agg[(size_t)dd2 * 64 + o], s + hb_s[nloc][o]);
        }
    }
}

// GRU; epilogue: hb = newh @ b_e2, hb16/hb16lo = split(newh); agg re-zeroed
__global__ __launch_bounds__(256) void k_gru(
    float* __restrict__ agg, const float* __restrict__ b_conv,
    const float* __restrict__ w_ih, const float* __restrict__ w_hh,
    const float* __restrict__ b_ih, const float* __restrict__ b_hh,
    const float* __restrict__ b2e,
    float* __restrict__ h, float* __restrict__ hb,
    unsigned short* __restrict__ hb16, unsigned short* __restrict__ hb16lo)
{
    int tid = threadIdx.x;
    int o = tid & 63, grp = tid >> 6;
    int vbase = blockIdx.x * 16;
    __shared__ float xl[16][68], hl[16][68];
    for (int idx = tid; idx < 16 * 64; idx += 256) {
        int n = idx >> 6, i = idx & 63;
        size_t p = (size_t)(vbase + n) * H + i;
        float a = agg[p];
        agg[p] = 0.f;
        xl[n][i] = fmaxf(a + b_conv[i], 0.f);
        hl[n][i] = h[p];
    }
    __syncthreads();
    float gir[4], giz[4], gin[4], ghr[4], ghz[4], ghn[4];
    #pragma unroll
    for (int n = 0; n < 4; ++n) {
        gir[n] = b_ih[o];       ghr[n] = b_hh[o];
        giz[n] = b_ih[64 + o];  ghz[n] = b_hh[64 + o];
        gin[n] = b_ih[128 + o]; ghn[n] = b_hh[128 + o];
    }
    const float4* wir = (const float4*)(w_ih + (size_t)o * H);
    const float4* wiz = (const float4*)(w_ih + (size_t)(64 + o) * H);
    const float4* win = (const float4*)(w_ih + (size_t)(128 + o) * H);
    const float4* whr = (const float4*)(w_hh + (size_t)o * H);
    const float4* whz = (const float4*)(w_hh + (size_t)(64 + o) * H);
    const float4* whn = (const float4*)(w_hh + (size_t)(128 + o) * H);
    #pragma unroll 4
    for (int qq = 0; qq < H / 4; ++qq) {
        float4 a1 = wir[qq], a2 = wiz[qq], a3 = win[qq];
        float4 c1 = whr[qq], c2 = whz[qq], c3 = whn[qq];
        #pragma unroll
        for (int n = 0; n < 4; ++n) {
            float4 xv = *(const float4*)&xl[grp * 4 + n][qq * 4];
            float4 hv = *(const float4*)&hl[grp * 4 + n][qq * 4];
            gir[n] += dot4(a1, xv); giz[n] += dot4(a2, xv); gin[n] += dot4(a3, xv);
            ghr[n] += dot4(c1, hv); ghz[n] += dot4(c2, hv); ghn[n] += dot4(c3, hv);
        }
    }
    float newh[4];
    #pragma unroll
    for (int n = 0; n < 4; ++n) {
        float hv = hl[grp * 4 + n][o];
        float r = 1.f / (1.f + __expf(-(gir[n] + ghr[n])));
        float z = 1.f / (1.f + __expf(-(giz[n] + ghz[n])));
        float na = gin[n] + r * ghn[n];
        float tn = 1.f - 2.f / (__expf(2.f * na) + 1.f);   // tanh
        newh[n] = (1.f - z) * tn + z * hv;
        size_t p = (size_t)(vbase + grp * 4 + n) * H + o;
        h[p] = newh[n];
        unsigned short hi = f2bf(newh[n]);
        hb16[p] = hi;
        hb16lo[p] = f2bf(newh[n] - bfbits(hi));
    }
    __syncthreads();
    #pragma unroll
    for (int n = 0; n < 4; ++n) xl[grp * 4 + n][o] = newh[n];
    __syncthreads();
    float hbacc[4] = {0.f, 0.f, 0.f, 0.f};
    for (int i = 0; i < H; ++i) {
        float w = b2e[i * 64 + o];
        #pragma unroll
        for (int n = 0; n < 4; ++n) hbacc[n] += xl[grp * 4 + n][i] * w;
    }
    #pragma unroll
    for (int n = 0; n < 4; ++n)
        hb[(size_t)(vbase + grp * 4 + n) * H + o] = hbacc[n];
}

// out = relu(h @ w_d1.T + b_d1) @ w_d2.T + b_d2  -> fp32
__global__ __launch_bounds__(64) void k_decoder(
    const float* __restrict__ h,
    const float* __restrict__ w1, const float* __restrict__ b1,
    const float* __restrict__ w2, const float* __restrict__ b2,
    float* __restrict__ out)
{
    int v = blockIdx.x, t = threadIdx.x;
    __shared__ float hl[H], tl[H];
    hl[t] = h[(size_t)v * H + t];
    __syncthreads();
    float acc = b1[t];
    const float4* wr = (const float4*)(w1 + (size_t)t * H);
    #pragma unroll
    for (int q = 0; q < H / 4; ++q) acc += dot4(wr[q], *(const float4*)&hl[q * 4]);
    tl[t] = fmaxf(acc, 0.f);
    __syncthreads();
    float acc2 = b2[t];
    const float4* wr2 = (const float4*)(w2 + (size_t)t * H);
    #pragma unroll
    for (int q = 0; q < H / 4; ++q) acc2 += dot4(wr2[q], *(const float4*)&tl[q * 4]);
    out[(size_t)v * OUT_F + t] = acc2;
}

extern "C" void kernel_launch(void* const* d_in, const int* in_sizes, int n_in,
                              void* d_out, int out_size, void* d_ws, size_t ws_size,
                              hipStream_t stream) {
    const float* nf     = (const float*)d_in[0];
    const float* ef     = (const float*)d_in[1];
    const int* src      = (const int*)d_in[2];
    const int* dst      = (const int*)d_in[3];
    const float* w_p1   = (const float*)d_in[4];
    const float* b_p1   = (const float*)d_in[5];
    const float* w_p2   = (const float*)d_in[6];
    const float* b_p2   = (const float*)d_in[7];
    const float* w_e1   = (const float*)d_in[8];
    const float* b_e1   = (const float*)d_in[9];
    const float* w_e2   = (const float*)d_in[10];
    const float* b_e2   = (const float*)d_in[11];
    const float* b_conv = (const float*)d_in[12];
    const float* w_ih   = (const float*)d_in[13];
    const float* w_hh   = (const float*)d_in[14];
    const float* b_ih   = (const float*)d_in[15];
    const float* b_hh   = (const float*)d_in[16];
    const float* w_d1   = (const float*)d_in[17];
    const float* b_d1   = (const float*)d_in[18];
    const float* w_d2   = (const float*)d_in[19];
    const float* b_d2   = (const float*)d_in[20];

    // workspace layout (~47.8 MB, offsets 1024-aligned)
    char* ws = (char*)d_ws;
    size_t off = 0;
    unsigned short* g      = (unsigned short*)(ws + off); off += 25600000;   // E*128 bf16
    unsigned short* w2rr   = (unsigned short*)(ws + off); off += 1048576;    // 8192*64 bf16
    float* h               = (float*)(ws + off);          off += 5120000;    // V*64 f32
    float* agg             = (float*)(ws + off);          off += 5120000;
    float* hb              = (float*)(ws + off);          off += 5120000;
    unsigned short* hb16   = (unsigned short*)(ws + off); off += 2560000;    // V*64 bf16
    unsigned short* hb16lo = (unsigned short*)(ws + off); off += 2560000;
    int* deg               = (int*)(ws + off);            off += 80896;
    int* cursor            = (int*)(ws + off);            off += 80896;
    int* rowptr            = (int*)(ws + off);            off += 80896;      // V+1 ints
    int* esort             = (int*)(ws + off);            off += 400384;     // E ints

    k_project<<<V_N / 4, 256, 0, stream>>>(nf, w_p1, b_p1, w_p2, b_p2, b_e2,
                                           h, agg, hb, hb16, hb16lo, deg);
    k_edge_g<<<E_N / 32, 256, 0, stream>>>(ef, w_e1, b_e1, g);
    k_w2rr<<<2048, 256, 0, stream>>>(w_e2, w2rr);
    k_hist<<<(E_N + 255) / 256, 256, 0, stream>>>(src, deg);
    k_scan<<<1, 256, 0, stream>>>(deg, rowptr, cursor);
    k_scatter<<<(E_N + 255) / 256, 256, 0, stream>>>(src, cursor, esort);

    for (int s = 0; s < STEPS; ++s) {
        k_fused<<<V_N / 16, 256, 0, stream>>>(hb16, hb16lo, w2rr, g, hb,
                                              rowptr, esort, src, dst, agg);
        k_gru<<<V_N / 16, 256, 0, stream>>>(agg, b_conv, w_ih, w_hh, b_ih, b_hh,
                                            b_e2, h, hb, hb16, hb16lo);
    }
    k_decoder<<<V_N, 64, 0, stream>>>(h, w_d1, b_d1, w_d2, b_d2, (float*)d_out);
}

// Round 10
// 3713.166 us; speedup vs baseline: 1.5325x; 1.1690x over previous
//
#include <hip/hip_runtime.h>

#define V_N 20000
#define E_N 100000
#define NODE_IN_F 128
#define EDGE_IN_F 128
#define H 64
#define EDGE_HID 128
#define OUT_F 64
#define STEPS 9
#define OS 136                 // o-stride (elements) in n_lds
#define NS (8 * OS)            // node stride: 1088 elements
#define GST 136                // g_s row stride (elements)
#define NED_CAP 128            // staged-edge cap (mean 80, sd ~9; P(>128) ~ 3e-8)

typedef __attribute__((ext_vector_type(8))) short bf16x8;
typedef __attribute__((ext_vector_type(4))) float f32x4;

__device__ __forceinline__ unsigned short f2bf(float f) {
    union { float f; unsigned int u; } v; v.f = f;
    unsigned int u = v.u;
    unsigned int r = (u + 0x7fffu + ((u >> 16) & 1u)) >> 16;  // RNE
    return (unsigned short)r;
}
__device__ __forceinline__ float bfbits(unsigned int u16) {
    union { unsigned int u; float f; } v; v.u = u16 << 16; return v.f;
}
// fused dot of 2 packed bf16 pairs + accumulator: c += a[0]*b[0] + a[1]*b[1]
__device__ __forceinline__ float dot2b(unsigned int a, unsigned int b, float c) {
#if __has_builtin(__builtin_amdgcn_fdot2_f32_bf16)
    typedef __attribute__((ext_vector_type(2))) __bf16 bf2;
    union { unsigned int u; bf2 v; } ua, ub;
    ua.u = a; ub.u = b;
    return __builtin_amdgcn_fdot2_f32_bf16(ua.v, ub.v, c, false);
#else
    union { unsigned int u; float f; } alo, ahi, blo, bhi;
    alo.u = a << 16; ahi.u = a & 0xffff0000u;
    blo.u = b << 16; bhi.u = b & 0xffff0000u;
    return c + alo.f * blo.f + ahi.f * bhi.f;
#endif
}
__device__ __forceinline__ float dot4(float4 w, float4 x) {
    return w.x * x.x + w.y * x.y + w.z * x.z + w.w * x.w;
}

// h0 = relu(nf@w1.T+b1)@w2.T+b2; zero agg & deg; hb = h0 @ b_e2; hb16/hb16lo = split(h0)
__global__ __launch_bounds__(256) void k_project(
    const float* __restrict__ nf,
    const float* __restrict__ w1, const float* __restrict__ b1,
    const float* __restrict__ w2, const float* __restrict__ b2,
    const float* __restrict__ b2e,
    float* __restrict__ h, float* __restrict__ agg, float* __restrict__ hb,
    unsigned short* __restrict__ hb16, unsigned short* __restrict__ hb16lo,
    int* __restrict__ deg)
{
    int wv = threadIdx.x >> 6, t = threadIdx.x & 63;
    int v = blockIdx.x * 4 + wv;
    __shared__ float x[4][132], tm[4][68];
    const float* row = nf + (size_t)v * NODE_IN_F;
    x[wv][t] = row[t];
    x[wv][t + 64] = row[t + 64];
    agg[(size_t)v * H + t] = 0.f;
    if (t == 0) deg[v] = 0;
    __syncthreads();
    float acc = b1[t];
    const float4* wr = (const float4*)(w1 + (size_t)t * NODE_IN_F);
    #pragma unroll
    for (int q = 0; q < NODE_IN_F / 4; ++q) acc += dot4(wr[q], *(const float4*)&x[wv][q * 4]);
    tm[wv][t] = fmaxf(acc, 0.f);
    __syncthreads();
    float acc2 = b2[t];
    const float4* wr2 = (const float4*)(w2 + (size_t)t * H);
    #pragma unroll
    for (int q = 0; q < H / 4; ++q) acc2 += dot4(wr2[q], *(const float4*)&tm[wv][q * 4]);
    size_t p = (size_t)v * H + t;
    h[p] = acc2;
    unsigned short hi = f2bf(acc2);
    hb16[p] = hi;
    hb16lo[p] = f2bf(acc2 - bfbits(hi));
    __syncthreads();
    x[wv][t] = acc2;
    __syncthreads();
    float acc3 = 0.f;
    for (int i = 0; i < H; ++i) acc3 += x[wv][i] * b2e[i * 64 + t];
    hb[p] = acc3;
}

// g = relu(ef @ w_e1.T + b_e1) -> (E,128) bf16
__global__ __launch_bounds__(256) void k_edge_g(
    const float* __restrict__ ef,
    const float* __restrict__ w1, const float* __restrict__ b1,
    unsigned short* __restrict__ g)
{
    int tid = threadIdx.x;
    int e0 = blockIdx.x * 32;
    int c = tid & 127, eg = tid >> 7;
    __shared__ float xe[32][132];
    for (int idx = tid; idx < 1024; idx += 256) {
        int e = idx >> 5, kq = idx & 31;
        float4 v = *(const float4*)(ef + (size_t)(e0 + e) * EDGE_IN_F + kq * 4);
        *(float4*)&xe[e][kq * 4] = v;
    }
    __syncthreads();
    float acc[16];
    #pragma unroll
    for (int j = 0; j < 16; ++j) acc[j] = b1[c];
    const float4* wr = (const float4*)(w1 + (size_t)c * EDGE_IN_F);
    for (int kb = 0; kb < EDGE_IN_F / 4; ++kb) {
        float4 w = wr[kb];
        #pragma unroll
        for (int j = 0; j < 16; ++j) {
            float4 x = *(const float4*)&xe[eg * 16 + j][kb * 4];
            acc[j] += dot4(w, x);
        }
    }
    #pragma unroll
    for (int j = 0; j < 16; ++j)
        g[(size_t)(e0 + eg * 16 + j) * EDGE_HID + c] = f2bf(fmaxf(acc[j], 0.f));
}

// w2rr[c][i] = bf16(w_e2[(i*64+o)*128 + k]), c = o*128+k. (8192 x 64 bf16, 1 MB)
__global__ __launch_bounds__(256) void k_w2rr(
    const float* __restrict__ w2, unsigned short* __restrict__ w2rr)
{
    int f = blockIdx.x * 256 + threadIdx.x;   // 0..524287
    int i = f & 63;
    int c = f >> 6;
    int o = c >> 7;
    int k = c & 127;
    w2rr[f] = f2bf(w2[(size_t)(i * 64 + o) * 128 + k]);
}

// CSR build (src static; rebuilt identically every call)
__global__ __launch_bounds__(256) void k_hist(const int* __restrict__ src, int* __restrict__ deg) {
    int e = blockIdx.x * 256 + threadIdx.x;
    if (e < E_N) atomicAdd(&deg[src[e]], 1);
}

__global__ __launch_bounds__(256) void k_scan(
    const int* __restrict__ deg, int* __restrict__ rowptr, int* __restrict__ cursor)
{
    const int CH = 79;   // 256*79 >= V_N
    int t = threadIdx.x;
    __shared__ int part[256];
    int base = t * CH, s = 0;
    for (int j = 0; j < CH; ++j) { int v = base + j; if (v < V_N) s += deg[v]; }
    part[t] = s;
    __syncthreads();
    if (t == 0) { int run = 0; for (int i = 0; i < 256; ++i) { int x = part[i]; part[i] = run; run += x; } }
    __syncthreads();
    int run = part[t];
    for (int j = 0; j < CH; ++j) {
        int v = base + j;
        if (v < V_N) { rowptr[v] = run; cursor[v] = run; run += deg[v]; }
    }
    if (t == 255) rowptr[V_N] = E_N;
}

__global__ __launch_bounds__(256) void k_scatter(
    const int* __restrict__ src, int* __restrict__ cursor, int* __restrict__ esort)
{
    int e = blockIdx.x * 256 + threadIdx.x;
    if (e < E_N) {
        int p = atomicAdd(&cursor[src[e]], 1);
        esort[p] = e;
    }
}

// Fused NNConv step: block = 16 nodes + their out-edges (CSR), 8 c-chunks of 1024.
// One-time staging: edge meta (packed dst<<4|nloc), g rows (LDS), hb -> Phase B
// is fully LDS-resident (no per-iteration global loads).
// Phase A (MFMA, verified layouts): N[n][o][k] tile into n_lds.
// Phase B: wave per edge; lane=(og,kg); g reads are LDS broadcasts; dot2 bf16
// (HW v_dot2 when available); butterfly over kg; 8-lane coalesced atomicAdd.
__global__ __launch_bounds__(256) void k_fused(
    const unsigned short* __restrict__ hb16, const unsigned short* __restrict__ hb16lo,
    const unsigned short* __restrict__ w2rr, const unsigned short* __restrict__ g,
    const float* __restrict__ hb, const int* __restrict__ rowptr,
    const int* __restrict__ esort, const int* __restrict__ src,
    const int* __restrict__ dst, float* __restrict__ agg)
{
    int tid = threadIdx.x;
    int wv = tid >> 6, lane = tid & 63;
    int m = lane & 15, q = lane >> 4;
    int nb = blockIdx.x * 16;
    __shared__ unsigned short n_lds[16 * NS];        // 34816 B
    __shared__ unsigned short g_s[NED_CAP * GST];    // 34816 B
    __shared__ int ed_pack[NED_CAP], ed_eid[NED_CAP];
    __shared__ float hb_s[16][68];
    int r0 = rowptr[nb], r1 = rowptr[nb + 16];
    int ntot = r1 - r0;
    int ned = ntot < NED_CAP ? ntot : NED_CAP;
    // ---- stage 1: edge metadata + hb ----
    for (int idx = tid; idx < ned; idx += 256) {
        int e = esort[r0 + idx];
        ed_eid[idx] = e;
        ed_pack[idx] = (dst[e] << 4) | (src[e] - nb);
    }
    for (int idx = tid; idx < 1024; idx += 256) {
        int n = idx >> 6, i = idx & 63;
        hb_s[n][i] = hb[(size_t)(nb + n) * 64 + i];
    }
    // A fragments: 16 node rows (lane m = node nb+m), hi/lo split, K=64 over i
    const unsigned short* pa = hb16 + (size_t)(nb + m) * 64 + q * 8;
    const unsigned short* pl = hb16lo + (size_t)(nb + m) * 64 + q * 8;
    bf16x8 ah0 = *(const bf16x8*)(pa);
    bf16x8 ah1 = *(const bf16x8*)(pa + 32);
    bf16x8 al0 = *(const bf16x8*)(pl);
    bf16x8 al1 = *(const bf16x8*)(pl + 32);
    int og = lane >> 3, kg = lane & 7;
    __syncthreads();
    // ---- stage 2: g rows -> LDS (bulk, coalesced, massively outstanding) ----
    for (int idx = tid; idx < ned * 16; idx += 256) {
        int j = idx >> 4, u = idx & 15;
        int e = ed_eid[j];
        uint4 val = ((const uint4*)(g + (size_t)e * EDGE_HID))[u];
        *(uint4*)&g_s[j * GST + u * 8] = val;
    }
    // (first Phase A -> B barrier covers stage-2 completion)

    for (int cc = 0; cc < 8; ++cc) {
        if (cc) __syncthreads();   // previous chunk's Phase-B reads complete
        // ---- Phase A ----
        #pragma unroll 4
        for (int t = 0; t < 16; ++t) {
            int tile = wv * 16 + t;               // 0..63
            int c0 = cc * 1024 + tile * 16;
            const unsigned short* pb = w2rr + (size_t)(c0 + m) * 64 + q * 8;
            bf16x8 b0 = *(const bf16x8*)(pb);
            bf16x8 b1 = *(const bf16x8*)(pb + 32);
            f32x4 d = {0.f, 0.f, 0.f, 0.f};
            d = __builtin_amdgcn_mfma_f32_16x16x32_bf16(al0, b0, d, 0, 0, 0);
            d = __builtin_amdgcn_mfma_f32_16x16x32_bf16(al1, b1, d, 0, 0, 0);
            d = __builtin_amdgcn_mfma_f32_16x16x32_bf16(ah0, b0, d, 0, 0, 0);
            d = __builtin_amdgcn_mfma_f32_16x16x32_bf16(ah1, b1, d, 0, 0, 0);
            int cl = tile * 16 + m;               // 0..1023
            int ol = cl >> 7, k = cl & 127;
            #pragma unroll
            for (int r = 0; r < 4; ++r) {
                int n = q * 4 + r;
                n_lds[n * NS + ol * OS + k] = f2bf(d[r]);
            }
        }
        __syncthreads();
        // ---- Phase B (all-LDS) ----
        int o = cc * 8 + og;
        for (int j = wv; j < ned; j += 4) {
            int pk = ed_pack[j];
            int nloc = pk & 15;
            int dd = pk >> 4;
            const uint4* gp = (const uint4*)&g_s[j * GST + kg * 16];
            uint4 g0 = gp[0], g1 = gp[1];
            const uint4* np = (const uint4*)&n_lds[nloc * NS + og * OS + kg * 16];
            uint4 n0 = np[0], n1 = np[1];
            float s0 = 0.f, s1 = 0.f;
            s0 = dot2b(g0.x, n0.x, s0); s1 = dot2b(g0.y, n0.y, s1);
            s0 = dot2b(g0.z, n0.z, s0); s1 = dot2b(g0.w, n0.w, s1);
            s0 = dot2b(g1.x, n1.x, s0); s1 = dot2b(g1.y, n1.y, s1);
            s0 = dot2b(g1.z, n1.z, s0); s1 = dot2b(g1.w, n1.w, s1);
            float s = s0 + s1;
            s += __shfl_xor(s, 1);
            s += __shfl_xor(s, 2);
            s += __shfl_xor(s, 4);
            if (kg == 0)
                atomicAdd(&agg[(size_t)dd * 64 + o], s + hb_s[nloc][o]);
        }
        // overflow path (ntot > NED_CAP): statistically never, correctness only
        for (int jj = NED_CAP + wv; jj < ntot; jj += 4) {
            int e = esort[r0 + jj];
            int nloc = src[e] - nb;
            int dd2 = dst[e];
            const uint4* gp = (const uint4*)(g + (size_t)e * EDGE_HID + kg * 16);
            uint4 g0 = gp[0], g1 = gp[1];
            const uint4* np = (const uint4*)&n_lds[nloc * NS + og * OS + kg * 16];
            uint4 n0 = np[0], n1 = np[1];
            float s = 0.f;
            s = dot2b(g0.x, n0.x, s); s = dot2b(g0.y, n0.y, s);
            s = dot2b(g0.z, n0.z, s); s = dot2b(g0.w, n0.w, s);
            s = dot2b(g1.x, n1.x, s); s = dot2b(g1.y, n1.y, s);
            s = dot2b(g1.z, n1.z, s); s = dot2b(g1.w, n1.w, s);
            s += __shfl_xor(s, 1);
            s += __shfl_xor(s, 2);
            s += __shfl_xor(s, 4);
            if (kg == 0)
                atomicAdd(&agg[(size_t)dd2 * 64 + o], s + hb_s[nloc][o]);
        }
    }
}

// GRU; epilogue: hb = newh @ b_e2, hb16/hb16lo = split(newh); agg re-zeroed
__global__ __launch_bounds__(256) void k_gru(
    float* __restrict__ agg, const float* __restrict__ b_conv,
    const float* __restrict__ w_ih, const float* __restrict__ w_hh,
    const float* __restrict__ b_ih, const float* __restrict__ b_hh,
    const float* __restrict__ b2e,
    float* __restrict__ h, float* __restrict__ hb,
    unsigned short* __restrict__ hb16, unsigned short* __restrict__ hb16lo)
{
    int tid = threadIdx.x;
    int o = tid & 63, grp = tid >> 6;
    int vbase = blockIdx.x * 16;
    __shared__ float xl[16][68], hl[16][68];
    for (int idx = tid; idx < 16 * 64; idx += 256) {
        int n = idx >> 6, i = idx & 63;
        size_t p = (size_t)(vbase + n) * H + i;
        float a = agg[p];
        agg[p] = 0.f;
        xl[n][i] = fmaxf(a + b_conv[i], 0.f);
        hl[n][i] = h[p];
    }
    __syncthreads();
    float gir[4], giz[4], gin[4], ghr[4], ghz[4], ghn[4];
    #pragma unroll
    for (int n = 0; n < 4; ++n) {
        gir[n] = b_ih[o];       ghr[n] = b_hh[o];
        giz[n] = b_ih[64 + o];  ghz[n] = b_hh[64 + o];
        gin[n] = b_ih[128 + o]; ghn[n] = b_hh[128 + o];
    }
    const float4* wir = (const float4*)(w_ih + (size_t)o * H);
    const float4* wiz = (const float4*)(w_ih + (size_t)(64 + o) * H);
    const float4* win = (const float4*)(w_ih + (size_t)(128 + o) * H);
    const float4* whr = (const float4*)(w_hh + (size_t)o * H);
    const float4* whz = (const float4*)(w_hh + (size_t)(64 + o) * H);
    const float4* whn = (const float4*)(w_hh + (size_t)(128 + o) * H);
    #pragma unroll 4
    for (int qq = 0; qq < H / 4; ++qq) {
        float4 a1 = wir[qq], a2 = wiz[qq], a3 = win[qq];
        float4 c1 = whr[qq], c2 = whz[qq], c3 = whn[qq];
        #pragma unroll
        for (int n = 0; n < 4; ++n) {
            float4 xv = *(const float4*)&xl[grp * 4 + n][qq * 4];
            float4 hv = *(const float4*)&hl[grp * 4 + n][qq * 4];
            gir[n] += dot4(a1, xv); giz[n] += dot4(a2, xv); gin[n] += dot4(a3, xv);
            ghr[n] += dot4(c1, hv); ghz[n] += dot4(c2, hv); ghn[n] += dot4(c3, hv);
        }
    }
    float newh[4];
    #pragma unroll
    for (int n = 0; n < 4; ++n) {
        float hv = hl[grp * 4 + n][o];
        float r = 1.f / (1.f + __expf(-(gir[n] + ghr[n])));
        float z = 1.f / (1.f + __expf(-(giz[n] + ghz[n])));
        float na = gin[n] + r * ghn[n];
        float tn = 1.f - 2.f / (__expf(2.f * na) + 1.f);   // tanh
        newh[n] = (1.f - z) * tn + z * hv;
        size_t p = (size_t)(vbase + grp * 4 + n) * H + o;
        h[p] = newh[n];
        unsigned short hi = f2bf(newh[n]);
        hb16[p] = hi;
        hb16lo[p] = f2bf(newh[n] - bfbits(hi));
    }
    __syncthreads();
    #pragma unroll
    for (int n = 0; n < 4; ++n) xl[grp * 4 + n][o] = newh[n];
    __syncthreads();
    float hbacc[4] = {0.f, 0.f, 0.f, 0.f};
    for (int i = 0; i < H; ++i) {
        float w = b2e[i * 64 + o];
        #pragma unroll
        for (int n = 0; n < 4; ++n) hbacc[n] += xl[grp * 4 + n][i] * w;
    }
    #pragma unroll
    for (int n = 0; n < 4; ++n)
        hb[(size_t)(vbase + grp * 4 + n) * H + o] = hbacc[n];
}

// out = relu(h @ w_d1.T + b_d1) @ w_d2.T + b_d2  -> fp32
__global__ __launch_bounds__(64) void k_decoder(
    const float* __restrict__ h,
    const float* __restrict__ w1, const float* __restrict__ b1,
    const float* __restrict__ w2, const float* __restrict__ b2,
    float* __restrict__ out)
{
    int v = blockIdx.x, t = threadIdx.x;
    __shared__ float hl[H], tl[H];
    hl[t] = h[(size_t)v * H + t];
    __syncthreads();
    float acc = b1[t];
    const float4* wr = (const float4*)(w1 + (size_t)t * H);
    #pragma unroll
    for (int q = 0; q < H / 4; ++q) acc += dot4(wr[q], *(const float4*)&hl[q * 4]);
    tl[t] = fmaxf(acc, 0.f);
    __syncthreads();
    float acc2 = b2[t];
    const float4* wr2 = (const float4*)(w2 + (size_t)t * H);
    #pragma unroll
    for (int q = 0; q < H / 4; ++q) acc2 += dot4(wr2[q], *(const float4*)&tl[q * 4]);
    out[(size_t)v * OUT_F + t] = acc2;
}

extern "C" void kernel_launch(void* const* d_in, const int* in_sizes, int n_in,
                              void* d_out, int out_size, void* d_ws, size_t ws_size,
                              hipStream_t stream) {
    const float* nf     = (const float*)d_in[0];
    const float* ef     = (const float*)d_in[1];
    const int* src      = (const int*)d_in[2];
    const int* dst      = (const int*)d_in[3];
    const float* w_p1   = (const float*)d_in[4];
    const float* b_p1   = (const float*)d_in[5];
    const float* w_p2   = (const float*)d_in[6];
    const float* b_p2   = (const float*)d_in[7];
    const float* w_e1   = (const float*)d_in[8];
    const float* b_e1   = (const float*)d_in[9];
    const float* w_e2   = (const float*)d_in[10];
    const float* b_e2   = (const float*)d_in[11];
    const float* b_conv = (const float*)d_in[12];
    const float* w_ih   = (const float*)d_in[13];
    const float* w_hh   = (const float*)d_in[14];
    const float* b_ih   = (const float*)d_in[15];
    const float* b_hh   = (const float*)d_in[16];
    const float* w_d1   = (const float*)d_in[17];
    const float* b_d1   = (const float*)d_in[18];
    const float* w_d2   = (const float*)d_in[19];
    const float* b_d2   = (const float*)d_in[20];

    // workspace layout (~47.8 MB, offsets 1024-aligned)
    char* ws = (char*)d_ws;
    size_t off = 0;
    unsigned short* g      = (unsigned short*)(ws + off); off += 25600000;   // E*128 bf16
    unsigned short* w2rr   = (unsigned short*)(ws + off); off += 1048576;    // 8192*64 bf16
    float* h               = (float*)(ws + off);          off += 5120000;    // V*64 f32
    float* agg             = (float*)(ws + off);          off += 5120000;
    float* hb              = (float*)(ws + off);          off += 5120000;
    unsigned short* hb16   = (unsigned short*)(ws + off); off += 2560000;    // V*64 bf16
    unsigned short* hb16lo = (unsigned short*)(ws + off); off += 2560000;
    int* deg               = (int*)(ws + off);            off += 80896;
    int* cursor            = (int*)(ws + off);            off += 80896;
    int* rowptr            = (int*)(ws + off);            off += 80896;      // V+1 ints
    int* esort             = (int*)(ws + off);            off += 400384;     // E ints

    k_project<<<V_N / 4, 256, 0, stream>>>(nf, w_p1, b_p1, w_p2, b_p2, b_e2,
                                           h, agg, hb, hb16, hb16lo, deg);
    k_edge_g<<<E_N / 32, 256, 0, stream>>>(ef, w_e1, b_e1, g);
    k_w2rr<<<2048, 256, 0, stream>>>(w_e2, w2rr);
    k_hist<<<(E_N + 255) / 256, 256, 0, stream>>>(src, deg);
    k_scan<<<1, 256, 0, stream>>>(deg, rowptr, cursor);
    k_scatter<<<(E_N + 255) / 256, 256, 0, stream>>>(src, cursor, esort);

    for (int s = 0; s < STEPS; ++s) {
        k_fused<<<V_N / 16, 256, 0, stream>>>(hb16, hb16lo, w2rr, g, hb,
                                              rowptr, esort, src, dst, agg);
        k_gru<<<V_N / 16, 256, 0, stream>>>(agg, b_conv, w_ih, w_hh, b_ih, b_hh,
                                            b_e2, h, hb, hb16, hb16lo);
    }
    k_decoder<<<V_N, 64, 0, stream>>>(h, w_d1, b_d1, w_d2, b_d2, (float*)d_out);
}